// Round 8
// baseline (2308.597 us; speedup 1.0000x reference)
//
#include <hip/hip_runtime.h>

// V=10000, R=8192, D=1024, B=1024, L=64, M=65536
// R8: (1) k_xw/k_mlp staging via __builtin_amdgcn_global_load_lds width=16
// (m97 structure; R3-audited layouts — infra, not gl16, killed R3/R4).
// (2) k_step: barrier-free K-loop, fragments loaded global->VGPR directly
// (h + Whh are L2-resident; no LDS staging, no syncthreads, compiler free to
// software-pipeline with fine-grained vmcnt).
#define D_DIM   1024
#define L_SEQ   64
#define B_BATCH 1024
#define M_NODES 65536
#define R_RULES 8192
#define V_VOCAB 10000

typedef unsigned short bf16_t;
typedef __attribute__((ext_vector_type(8))) short s8v;   // 8 bf16 (MFMA A/B frag)
typedef __attribute__((ext_vector_type(4))) float f4v;   // MFMA C/D frag

static __device__ __forceinline__ float bf2f(unsigned short u) {
    union { unsigned int i; float f; } v; v.i = ((unsigned int)u) << 16; return v.f;
}
static __device__ __forceinline__ unsigned short f2bf(float f) {  // RNE
    union { float f; unsigned int i; } v; v.f = f;
    return (unsigned short)((v.i + 0x7FFFu + ((v.i >> 16) & 1u)) >> 16);
}
static __device__ __forceinline__ float fast_tanh(float x) {
    float xc = fminf(fmaxf(x, -15.f), 15.f);
    float t  = __expf(2.f * xc);
    return (t - 1.f) * __builtin_amdgcn_rcpf(t + 1.f);
}

// async 16B global->LDS (wave-uniform LDS base + lane*16)
typedef const __attribute__((address_space(1))) unsigned int* gas_t;
typedef __attribute__((address_space(3))) unsigned int* las_t;
static __device__ __forceinline__ void gl16(const void* g, void* l) {
    __builtin_amdgcn_global_load_lds((gas_t)g, (las_t)l, 16, 0, 0);
}

static __device__ __forceinline__ f4v mfma16(s8v a, s8v b, f4v c) {
    return __builtin_amdgcn_mfma_f32_16x16x32_bf16(a, b, c, 0, 0, 0);
}

// ---------------------------------------------------------------------------
__global__ __launch_bounds__(256) void k_cvt_emb(
    const float* __restrict__ emb, bf16_t* __restrict__ embB)
{
    size_t i = ((size_t)blockIdx.x * 256 + threadIdx.x) * 8;
    f4v x0 = *(const f4v*)&emb[i];
    f4v x1 = *(const f4v*)&emb[i + 4];
    s8v o;
    o[0] = (short)f2bf(x0.x); o[1] = (short)f2bf(x0.y);
    o[2] = (short)f2bf(x0.z); o[3] = (short)f2bf(x0.w);
    o[4] = (short)f2bf(x1.x); o[5] = (short)f2bf(x1.y);
    o[6] = (short)f2bf(x1.z); o[7] = (short)f2bf(x1.w);
    *(s8v*)&embB[i] = o;
}

__global__ __launch_bounds__(256) void k_transcvt(
    const float* __restrict__ src, bf16_t* __restrict__ dst, int K, int N)
{
    __shared__ float s[32][33];
    int n0 = blockIdx.x * 32, k0 = blockIdx.y * 32;
    int tx = threadIdx.x, ty = threadIdx.y;  // (32,8)
#pragma unroll
    for (int i = 0; i < 4; ++i)
        s[ty + i * 8][tx] = src[(size_t)(k0 + ty + i * 8) * N + n0 + tx];
    __syncthreads();
#pragma unroll
    for (int i = 0; i < 4; ++i)
        dst[(size_t)(n0 + ty + i * 8) * K + k0 + tx] = f2bf(s[tx][ty + i * 8]);
}

__global__ __launch_bounds__(256) void k_cvt_h0(
    const float* __restrict__ h0, bf16_t* __restrict__ h0b)
{
    for (int u = threadIdx.x; u < D_DIM; u += 256) h0b[u] = f2bf(h0[u]);
}

// ---------------------------------------------------------------------------
// k_xw_mfma: XE[n,:] = bf16(embB[tokens[n],:] @ Wxh + bh)
// 128x128 tile, BK=32, global_load_lds staging (A = token gather).
// ---------------------------------------------------------------------------
__global__ __launch_bounds__(256) void k_xw_mfma(
    const int* __restrict__ tokens, const bf16_t* __restrict__ embB,
    const bf16_t* __restrict__ WxhT, const float* __restrict__ bh,
    bf16_t* __restrict__ XE)
{
    __shared__ bf16_t As[128 * 32];            // 8 KB
    __shared__ bf16_t Bs[128 * 32];            // 8 KB
    __shared__ float  epi[4][16][68];          // 17.4 KB (per-wave private)

    const int tid = threadIdx.x;
    const int w = tid >> 6, l = tid & 63;
    const int q = l >> 4, t16 = l & 15;
    const int wm = (w >> 1) * 64, wn = (w & 1) * 64;
    const int row0 = blockIdx.x * 128, col0 = blockIdx.y * 128;

    const bf16_t* arow[2];
#pragma unroll
    for (int r = 0; r < 2; ++r)
        arow[r] = embB + (size_t)tokens[row0 + (tid >> 2) + r * 64] * D_DIM + ((tid & 3) << 3);
    const bf16_t* brow[2];
#pragma unroll
    for (int r = 0; r < 2; ++r)
        brow[r] = WxhT + (size_t)(col0 + (tid >> 2) + r * 64) * D_DIM + ((tid & 3) << 3);

    f4v acc[4][4];
#pragma unroll
    for (int i = 0; i < 4; ++i)
#pragma unroll
        for (int j = 0; j < 4; ++j) acc[i][j] = (f4v)0.f;

    for (int k0 = 0; k0 < D_DIM; k0 += 32) {
        __syncthreads();                       // prev iter frag reads done
        gl16(arow[0] + k0, &As[tid * 8]);
        gl16(arow[1] + k0, &As[(256 + tid) * 8]);
        gl16(brow[0] + k0, &Bs[tid * 8]);
        gl16(brow[1] + k0, &Bs[(256 + tid) * 8]);
        __syncthreads();                       // DMA drained (vmcnt before barrier)
        s8v af[4], bfr[4];
#pragma unroll
        for (int ti = 0; ti < 4; ++ti)
            af[ti] = *(const s8v*)&As[(wm + ti * 16 + t16) * 32 + q * 8];
#pragma unroll
        for (int tj = 0; tj < 4; ++tj)
            bfr[tj] = *(const s8v*)&Bs[(wn + tj * 16 + t16) * 32 + q * 8];
#pragma unroll
        for (int ti = 0; ti < 4; ++ti)
#pragma unroll
            for (int tj = 0; tj < 4; ++tj)
                acc[ti][tj] = mfma16(af[ti], bfr[tj], acc[ti][tj]);
    }

    // barrier-free per-wave epilogue (epi[w] wave-private)
    const int lr = l >> 2, c16 = (l & 3) * 16;
    f4v bias[4];
#pragma unroll
    for (int u = 0; u < 4; ++u)
        bias[u] = *(const f4v*)&bh[col0 + wn + c16 + u * 4];
#pragma unroll
    for (int ti = 0; ti < 4; ++ti) {
#pragma unroll
        for (int tj = 0; tj < 4; ++tj)
#pragma unroll
            for (int rg = 0; rg < 4; ++rg)
                epi[w][q * 4 + rg][tj * 16 + t16] = acc[ti][tj][rg];
        s8v o0, o1;
#pragma unroll
        for (int u = 0; u < 8; ++u) {
            o0[u] = (short)f2bf(epi[w][lr][c16 + u]     + bias[u >> 2][u & 3]);
            o1[u] = (short)f2bf(epi[w][lr][c16 + 8 + u] + bias[2 + (u >> 2)][u & 3]);
        }
        size_t orow = (size_t)(row0 + wm + ti * 16 + lr) * D_DIM + col0 + wn + c16;
        *(s8v*)&XE[orow]     = o0;
        *(s8v*)&XE[orow + 8] = o1;
    }
}

// ---------------------------------------------------------------------------
// k_step_mfma (x64): y = tanh(XE[b*L+t,:] + h_prev[b,:] @ Whh); XE[..] = bf16(y)
// 64x64 tile, 512 threads (8 waves). NO LDS staging, NO K-loop barriers:
// A/B fragments loaded straight global->VGPR (h + Whh are L2-resident),
// depth-1 prefetch; compiler interleaves vmcnt with MFMA.
// Wave (wr,wc)=(w>>2,w&3): rows wr*32+[0,32), cols wc*16+[0,16).
// ---------------------------------------------------------------------------
__global__ __launch_bounds__(512) void k_step_mfma(
    const bf16_t* __restrict__ Abase, int strideRow,
    const bf16_t* __restrict__ WhhT, bf16_t* __restrict__ XE, int t)
{
    __shared__ float epi[8][16][20];           // 10.2 KB (per-wave private)

    const int tid = threadIdx.x;
    const int w = tid >> 6, l = tid & 63;
    const int q = l >> 4, t16 = l & 15;
    const int wr = w >> 2, wc = w & 3;
    const int row0 = blockIdx.x * 64, col0 = blockIdx.y * 64;

    // per-lane fragment pointers (frag = 16B at k-offset q*8, advancing by k0)
    const bf16_t* a0p = Abase + (size_t)(row0 + wr * 32 + t16)      * strideRow + q * 8;
    const bf16_t* a1p = Abase + (size_t)(row0 + wr * 32 + 16 + t16) * strideRow + q * 8;
    const bf16_t* bp  = WhhT  + (size_t)(col0 + wc * 16 + t16)      * D_DIM     + q * 8;

    f4v acc0 = (f4v)0.f, acc1 = (f4v)0.f;
    s8v a0 = *(const s8v*)a0p;
    s8v a1 = *(const s8v*)a1p;
    s8v bf = *(const s8v*)bp;

#pragma unroll 8
    for (int k0 = 0; k0 < D_DIM; k0 += 32) {
        int kn = (k0 + 32 < D_DIM) ? (k0 + 32) : k0;   // last iter: reload (discarded)
        s8v na0 = *(const s8v*)(a0p + kn);
        s8v na1 = *(const s8v*)(a1p + kn);
        s8v nbf = *(const s8v*)(bp + kn);
        acc0 = mfma16(a0, bf, acc0);
        acc1 = mfma16(a1, bf, acc1);
        a0 = na0; a1 = na1; bf = nbf;
    }

    // per-wave epilogue, no barriers
    const int lr = l >> 2, c4 = (l & 3) * 4;
    f4v accs[2] = {acc0, acc1};
#pragma unroll
    for (int ti = 0; ti < 2; ++ti) {
#pragma unroll
        for (int rg = 0; rg < 4; ++rg)
            epi[w][q * 4 + rg][t16] = accs[ti][rg];
        f4v v = *(const f4v*)&epi[w][lr][c4];
        int b = row0 + wr * 32 + ti * 16 + lr;
        size_t xi = ((size_t)b * L_SEQ + t) * D_DIM + col0 + wc * 16 + c4;
        unsigned long long xr = *(const unsigned long long*)&XE[xi];
        unsigned short xs[4];
        xs[0] = (unsigned short)(xr & 0xFFFF);
        xs[1] = (unsigned short)((xr >> 16) & 0xFFFF);
        xs[2] = (unsigned short)((xr >> 32) & 0xFFFF);
        xs[3] = (unsigned short)((xr >> 48) & 0xFFFF);
        unsigned long long ow = 0;
#pragma unroll
        for (int u = 0; u < 4; ++u) {
            unsigned short oo = f2bf(fast_tanh(bf2f(xs[u]) + v[u]));
            ow |= ((unsigned long long)oo) << (16 * u);
        }
        *(unsigned long long*)&XE[xi] = ow;
    }
}

// ---------------------------------------------------------------------------
// k_mlp_mfma: h = tanh(concat(XE[i],XE[j]) @ W1 + b1) fused with rule-dot:
// partials[cb][m] = dot(h[m, 64-col-slice], Wt2[r_idx[m], slice]). No h store.
// 128x128 tile, K=2048, global_load_lds staging, fast_tanh.
// ---------------------------------------------------------------------------
__global__ __launch_bounds__(256) void k_mlp_mfma(
    const int* __restrict__ i_idx, const int* __restrict__ j_idx,
    const bf16_t* __restrict__ XE, const bf16_t* __restrict__ W1T,
    const float* __restrict__ b1, const bf16_t* __restrict__ Wt2,
    const int* __restrict__ r_idx, float* __restrict__ partials)
{
    __shared__ bf16_t As[128 * 32];            // 8 KB
    __shared__ bf16_t Bs[128 * 32];            // 8 KB

    const int tid = threadIdx.x;
    const int w = tid >> 6, l = tid & 63;
    const int q = l >> 4, t16 = l & 15;
    const int wm = (w >> 1) * 64, wn = (w & 1) * 64;
    const int row0 = blockIdx.x * 128, col0 = blockIdx.y * 128;

    const bf16_t* pi[2]; const bf16_t* pj[2];
#pragma unroll
    for (int r = 0; r < 2; ++r) {
        int m = row0 + (tid >> 2) + r * 64;
        pi[r] = XE + (size_t)i_idx[m] * D_DIM + ((tid & 3) << 3);
        pj[r] = XE + (size_t)j_idx[m] * D_DIM - D_DIM + ((tid & 3) << 3);  // k in [1024,2048)
    }
    const bf16_t* brow[2];
#pragma unroll
    for (int r = 0; r < 2; ++r)
        brow[r] = W1T + (size_t)(col0 + (tid >> 2) + r * 64) * (2 * D_DIM) + ((tid & 3) << 3);

    f4v acc[4][4];
#pragma unroll
    for (int i = 0; i < 4; ++i)
#pragma unroll
        for (int j = 0; j < 4; ++j) acc[i][j] = (f4v)0.f;

    for (int k0 = 0; k0 < 2 * D_DIM; k0 += 32) {
        __syncthreads();
        gl16(((k0 < D_DIM) ? pi[0] : pj[0]) + k0, &As[tid * 8]);
        gl16(((k0 < D_DIM) ? pi[1] : pj[1]) + k0, &As[(256 + tid) * 8]);
        gl16(brow[0] + k0, &Bs[tid * 8]);
        gl16(brow[1] + k0, &Bs[(256 + tid) * 8]);
        __syncthreads();
        s8v af[4], bfr[4];
#pragma unroll
        for (int ti = 0; ti < 4; ++ti)
            af[ti] = *(const s8v*)&As[(wm + ti * 16 + t16) * 32 + q * 8];
#pragma unroll
        for (int tj = 0; tj < 4; ++tj)
            bfr[tj] = *(const s8v*)&Bs[(wn + tj * 16 + t16) * 32 + q * 8];
#pragma unroll
        for (int ti = 0; ti < 4; ++ti)
#pragma unroll
            for (int tj = 0; tj < 4; ++tj)
                acc[ti][tj] = mfma16(af[ti], bfr[tj], acc[ti][tj]);
    }

    // fused epilogue in C-layout: fast_tanh, dot with gathered rule row, 16-lane reduce
    const int cb = blockIdx.y * 2 + (w & 1);
#pragma unroll
    for (int ti = 0; ti < 4; ++ti) {
#pragma unroll
        for (int rg = 0; rg < 4; ++rg) {
            int m = row0 + wm + ti * 16 + q * 4 + rg;
            int r = r_idx[m];
            const bf16_t* wrow = Wt2 + (size_t)r * D_DIM + col0 + wn + t16;
            float pd = 0.f;
#pragma unroll
            for (int tj = 0; tj < 4; ++tj) {
                int col = col0 + wn + tj * 16 + t16;
                float h = fast_tanh(acc[ti][tj][rg] + b1[col]);
                pd += h * bf2f(wrow[tj * 16]);
            }
            pd += __shfl_xor(pd, 1);
            pd += __shfl_xor(pd, 2);
            pd += __shfl_xor(pd, 4);
            pd += __shfl_xor(pd, 8);
            if (t16 == 0)
                partials[(size_t)cb * M_NODES + m] = pd;
        }
    }
}

// ---------------------------------------------------------------------------
__global__ __launch_bounds__(256) void k_reduce(
    const float* __restrict__ partials, const int* __restrict__ r_idx,
    const float* __restrict__ b2, float* __restrict__ out)
{
    int m = blockIdx.x * 256 + threadIdx.x;
    float s = 0.f;
#pragma unroll
    for (int cb = 0; cb < 16; ++cb)
        s += partials[(size_t)cb * M_NODES + m];
    out[m] = s + b2[r_idx[m]];
}

// ---------------------------------------------------------------------------
extern "C" void kernel_launch(void* const* d_in, const int* in_sizes, int n_in,
                              void* d_out, int out_size, void* d_ws, size_t ws_size,
                              hipStream_t stream) {
    const int*   tokens = (const int*)  d_in[0];
    const int*   i_idx  = (const int*)  d_in[1];
    const int*   j_idx  = (const int*)  d_in[2];
    const int*   r_idx  = (const int*)  d_in[3];
    const float* emb    = (const float*)d_in[4];
    const float* Wxh    = (const float*)d_in[5];
    const float* Whh    = (const float*)d_in[6];
    const float* bh     = (const float*)d_in[7];
    const float* h0     = (const float*)d_in[8];
    const float* W1     = (const float*)d_in[9];
    const float* b1     = (const float*)d_in[10];
    const float* W2     = (const float*)d_in[11];
    const float* b2     = (const float*)d_in[12];
    float* out = (float*)d_out;

    // Workspace (~156 MiB). embB (20 MiB) aliases WhhT/W1T/Wt2 (22 MiB):
    // embB dead after k_xw_mfma; those conversions run after it.
    bf16_t* XE   = (bf16_t*)d_ws;                        // [B*L][D]  128 MiB
    bf16_t* WxhT = XE   + (size_t)M_NODES * D_DIM;       // [D][D]      2 MiB
    bf16_t* WhhT = WxhT + (size_t)D_DIM * D_DIM;         // [D][D]      2 MiB
    bf16_t* W1T  = WhhT + (size_t)D_DIM * D_DIM;         // [D][2D]     4 MiB
    bf16_t* Wt2  = W1T  + (size_t)2 * D_DIM * D_DIM;     // [R][D]     16 MiB
    bf16_t* embB = WhhT;                                 // [V][D]     20 MiB (alias)
    bf16_t* h0b  = Wt2  + (size_t)R_RULES * D_DIM;       // [D] (pad 2048)
    float*  par  = (float*)(h0b + 2048);                 // [16][M]     4 MiB

    // Phase 1: emb->bf16, Wxh, h0
    k_cvt_emb<<<V_VOCAB * D_DIM / 2048, 256, 0, stream>>>(emb, embB);
    k_transcvt<<<dim3(D_DIM / 32, D_DIM / 32), dim3(32, 8), 0, stream>>>(Wxh, WxhT, D_DIM, D_DIM);
    k_cvt_h0<<<1, 256, 0, stream>>>(h0, h0b);

    // Phase 2: XE = bf16(embB[tokens] @ Wxh + bh)   (last reader of embB)
    k_xw_mfma<<<dim3(M_NODES / 128, D_DIM / 128), 256, 0, stream>>>(tokens, embB, WxhT, bh, XE);

    // Phase 3: remaining weight conversions (overwrite embB region)
    k_transcvt<<<dim3(D_DIM / 32, D_DIM / 32), dim3(32, 8), 0, stream>>>(Whh, WhhT, D_DIM, D_DIM);
    k_transcvt<<<dim3(D_DIM / 32, 2 * D_DIM / 32), dim3(32, 8), 0, stream>>>(W1, W1T, 2 * D_DIM, D_DIM);
    k_transcvt<<<dim3(R_RULES / 32, D_DIM / 32), dim3(32, 8), 0, stream>>>(W2, Wt2, D_DIM, R_RULES);

    // Phase 4: 64 sequential RNN steps (in-place on XE)
    for (int t = 0; t < L_SEQ; ++t) {
        const bf16_t* Abase = (t == 0) ? h0b : (XE + (size_t)(t - 1) * D_DIM);
        int strideRow       = (t == 0) ? 0   : L_SEQ * D_DIM;
        k_step_mfma<<<dim3(B_BATCH / 64, D_DIM / 64), 512, 0, stream>>>(
            Abase, strideRow, WhhT, XE, t);
    }

    // Phase 5: MLP + fused rule-dot partials
    k_mlp_mfma<<<dim3(M_NODES / 128, D_DIM / 128), 256, 0, stream>>>(
        i_idx, j_idx, XE, W1T, b1, Wt2, r_idx, par);

    // Phase 6: deterministic reduce + b2
    k_reduce<<<M_NODES / 256, 256, 0, stream>>>(par, r_idx, b2, out);
}

// Round 9
// 1293.517 us; speedup vs baseline: 1.7847x; 1.7847x over previous
//
#include <hip/hip_runtime.h>

// V=10000, R=8192, D=1024, B=1024, L=64, M=65536
// R9 = R7 (1345 us: manual staging + VGPR prefetch everywhere) + XCD-aware
// block swizzle in k_xw/k_mlp. R8 taught: (1) gl16's 2-barrier loop loses the
// prefetch overlap R7 had (468->505); (2) direct-register k_step fragments are
// scatter-loaded and 4x redundant (9.4->23 us/step). Both reverted.
// New: k_mlp fetched 1.08 GB vs ~330 MB unique because the 8 col-blocks of a
// row-tile land on 8 different XCDs (round-robin); remap so each XCD owns 64
// row-tiles with col-chunks dispatch-adjacent -> A-gathers hit per-XCD L2.
#define D_DIM   1024
#define L_SEQ   64
#define B_BATCH 1024
#define M_NODES 65536
#define R_RULES 8192
#define V_VOCAB 10000

typedef unsigned short bf16_t;
typedef __attribute__((ext_vector_type(8))) short s8v;   // 8 bf16 (MFMA A/B frag)
typedef __attribute__((ext_vector_type(4))) short s4v;   // 4 bf16
typedef __attribute__((ext_vector_type(4))) float f4v;   // MFMA C/D frag

static __device__ __forceinline__ float bf2f(unsigned short u) {
    union { unsigned int i; float f; } v; v.i = ((unsigned int)u) << 16; return v.f;
}
static __device__ __forceinline__ unsigned short f2bf(float f) {  // RNE
    union { float f; unsigned int i; } v; v.f = f;
    return (unsigned short)((v.i + 0x7FFFu + ((v.i >> 16) & 1u)) >> 16);
}
static __device__ __forceinline__ float fast_tanh(float x) {
    float xc = fminf(fmaxf(x, -15.f), 15.f);
    float t  = __expf(2.f * xc);
    return (t - 1.f) * __builtin_amdgcn_rcpf(t + 1.f);
}

static __device__ __forceinline__ f4v mfma16(s8v a, s8v b, f4v c) {
    return __builtin_amdgcn_mfma_f32_16x16x32_bf16(a, b, c, 0, 0, 0);
}

// ---------------------------------------------------------------------------
__global__ __launch_bounds__(256) void k_cvt_emb(
    const float* __restrict__ emb, bf16_t* __restrict__ embB)
{
    size_t i = ((size_t)blockIdx.x * 256 + threadIdx.x) * 8;
    f4v x0 = *(const f4v*)&emb[i];
    f4v x1 = *(const f4v*)&emb[i + 4];
    s8v o;
    o[0] = (short)f2bf(x0.x); o[1] = (short)f2bf(x0.y);
    o[2] = (short)f2bf(x0.z); o[3] = (short)f2bf(x0.w);
    o[4] = (short)f2bf(x1.x); o[5] = (short)f2bf(x1.y);
    o[6] = (short)f2bf(x1.z); o[7] = (short)f2bf(x1.w);
    *(s8v*)&embB[i] = o;
}

__global__ __launch_bounds__(256) void k_transcvt(
    const float* __restrict__ src, bf16_t* __restrict__ dst, int K, int N)
{
    __shared__ float s[32][33];
    int n0 = blockIdx.x * 32, k0 = blockIdx.y * 32;
    int tx = threadIdx.x, ty = threadIdx.y;  // (32,8)
#pragma unroll
    for (int i = 0; i < 4; ++i)
        s[ty + i * 8][tx] = src[(size_t)(k0 + ty + i * 8) * N + n0 + tx];
    __syncthreads();
#pragma unroll
    for (int i = 0; i < 4; ++i)
        dst[(size_t)(n0 + ty + i * 8) * K + k0 + tx] = f2bf(s[tx][ty + i * 8]);
}

__global__ __launch_bounds__(256) void k_cvt_h0(
    const float* __restrict__ h0, bf16_t* __restrict__ h0b)
{
    for (int u = threadIdx.x; u < D_DIM; u += 256) h0b[u] = f2bf(h0[u]);
}

// ---------------------------------------------------------------------------
// k_xw_mfma: XE[n,:] = bf16(embB[tokens[n],:] @ Wxh + bh)
// 128x128 tile, BK=32, manual staging + VGPR prefetch, XCD swizzle.
// Grid: 4096 1-D blocks; xcd=i&7 owns rowTiles [xcd*64, xcd*64+64).
// ---------------------------------------------------------------------------
__global__ __launch_bounds__(256) void k_xw_mfma(
    const int* __restrict__ tokens, const bf16_t* __restrict__ embB,
    const bf16_t* __restrict__ WxhT, const float* __restrict__ bh,
    bf16_t* __restrict__ XE)
{
    __shared__ bf16_t As[128 * 32];            // 8 KB
    __shared__ bf16_t Bs[128 * 32];            // 8 KB
    __shared__ float  epi[4][16][68];          // 17.4 KB (per-wave private)

    const int bi  = blockIdx.x;
    const int xcd = bi & 7, j = bi >> 3;
    const int row0 = ((xcd << 6) + (j >> 3)) * 128;   // rowTile in [0,512)
    const int col0 = (j & 7) * 128;                   // colTile in [0,8)

    const int tid = threadIdx.x;
    const int w = tid >> 6, l = tid & 63;
    const int q = l >> 4, t16 = l & 15;
    const int wm = (w >> 1) * 64, wn = (w & 1) * 64;

    const bf16_t* arow[2];
#pragma unroll
    for (int r = 0; r < 2; ++r)
        arow[r] = embB + (size_t)tokens[row0 + (tid >> 2) + r * 64] * D_DIM + ((tid & 3) << 3);
    const bf16_t* brow[2];
#pragma unroll
    for (int r = 0; r < 2; ++r)
        brow[r] = WxhT + (size_t)(col0 + (tid >> 2) + r * 64) * D_DIM + ((tid & 3) << 3);

    f4v acc[4][4];
#pragma unroll
    for (int i = 0; i < 4; ++i)
#pragma unroll
        for (int jj = 0; jj < 4; ++jj) acc[i][jj] = (f4v)0.f;

    // prefetch k=0
    s8v a0 = *(const s8v*)(arow[0]);
    s8v a1 = *(const s8v*)(arow[1]);
    s8v b0 = *(const s8v*)(brow[0]);
    s8v b1 = *(const s8v*)(brow[1]);

    const int rr = tid >> 2, cc = (tid & 3) << 3;
    for (int k0 = 0; k0 < D_DIM; k0 += 32) {
        __syncthreads();                       // prev iter frag reads done
        *(s8v*)&As[rr * 32 + cc]        = a0;
        *(s8v*)&As[(rr + 64) * 32 + cc] = a1;
        *(s8v*)&Bs[rr * 32 + cc]        = b0;
        *(s8v*)&Bs[(rr + 64) * 32 + cc] = b1;
        int kn = k0 + 32;
        if (kn < D_DIM) {                      // issue next loads early
            a0 = *(const s8v*)(arow[0] + kn);
            a1 = *(const s8v*)(arow[1] + kn);
            b0 = *(const s8v*)(brow[0] + kn);
            b1 = *(const s8v*)(brow[1] + kn);
        }
        __syncthreads();
        s8v af[4], bfr[4];
#pragma unroll
        for (int ti = 0; ti < 4; ++ti)
            af[ti] = *(const s8v*)&As[(wm + ti * 16 + t16) * 32 + q * 8];
#pragma unroll
        for (int tj = 0; tj < 4; ++tj)
            bfr[tj] = *(const s8v*)&Bs[(wn + tj * 16 + t16) * 32 + q * 8];
#pragma unroll
        for (int ti = 0; ti < 4; ++ti)
#pragma unroll
            for (int tj = 0; tj < 4; ++tj)
                acc[ti][tj] = mfma16(af[ti], bfr[tj], acc[ti][tj]);
    }

    // barrier-free per-wave epilogue (epi[w] wave-private)
    const int lr = l >> 2, c16 = (l & 3) * 16;
    f4v bias[4];
#pragma unroll
    for (int u = 0; u < 4; ++u)
        bias[u] = *(const f4v*)&bh[col0 + wn + c16 + u * 4];
#pragma unroll
    for (int ti = 0; ti < 4; ++ti) {
#pragma unroll
        for (int tj = 0; tj < 4; ++tj)
#pragma unroll
            for (int rg = 0; rg < 4; ++rg)
                epi[w][q * 4 + rg][tj * 16 + t16] = acc[ti][tj][rg];
        s8v o0, o1;
#pragma unroll
        for (int u = 0; u < 8; ++u) {
            o0[u] = (short)f2bf(epi[w][lr][c16 + u]     + bias[u >> 2][u & 3]);
            o1[u] = (short)f2bf(epi[w][lr][c16 + 8 + u] + bias[2 + (u >> 2)][u & 3]);
        }
        size_t orow = (size_t)(row0 + wm + ti * 16 + lr) * D_DIM + col0 + wn + c16;
        *(s8v*)&XE[orow]     = o0;
        *(s8v*)&XE[orow + 8] = o1;
    }
}

// ---------------------------------------------------------------------------
// k_step_mfma (x64): y = tanh(XE[b*L+t,:] + h_prev[b,:] @ Whh); XE[..] = bf16(y)
// 64x64 tile, 512 threads (8 waves = 2/SIMD), SW-prefetch, fast_tanh.
// (R7 version verbatim — R8's direct-register variant was 2.4x slower.)
// ---------------------------------------------------------------------------
__global__ __launch_bounds__(512) void k_step_mfma(
    const bf16_t* __restrict__ Abase, int strideRow,
    const bf16_t* __restrict__ WhhT, bf16_t* __restrict__ XE, int t)
{
    __shared__ bf16_t As[64 * 32];             // 4 KB
    __shared__ bf16_t Bs[64 * 32];             // 4 KB
    __shared__ float  epi[8][16][20];          // 10.2 KB (per-wave private)

    const int tid = threadIdx.x;
    const int w = tid >> 6, l = tid & 63;
    const int q = l >> 4, t16 = l & 15;
    const int wr = w >> 2, wc = w & 3;
    const int row0 = blockIdx.x * 64, col0 = blockIdx.y * 64;

    const bf16_t* asrc = Abase + (size_t)(row0 + (tid >> 3)) * strideRow + ((tid & 7) << 2);
    const bf16_t* bsrc = WhhT + (size_t)(col0 + (tid >> 3)) * D_DIM + ((tid & 7) << 2);

    f4v acc[2];
    acc[0] = (f4v)0.f; acc[1] = (f4v)0.f;

    s4v rA = *(const s4v*)(asrc);
    s4v rB = *(const s4v*)(bsrc);

    const int srow = tid >> 3, scol = (tid & 7) << 2;
    for (int k0 = 0; k0 < D_DIM; k0 += 32) {
        __syncthreads();
        *(s4v*)&As[srow * 32 + scol] = rA;
        *(s4v*)&Bs[srow * 32 + scol] = rB;
        int kn = k0 + 32;
        if (kn < D_DIM) {
            rA = *(const s4v*)(asrc + kn);
            rB = *(const s4v*)(bsrc + kn);
        }
        __syncthreads();
        s8v af[2], bfr;
#pragma unroll
        for (int ti = 0; ti < 2; ++ti)
            af[ti] = *(const s8v*)&As[(wr * 32 + ti * 16 + t16) * 32 + q * 8];
        bfr = *(const s8v*)&Bs[(wc * 16 + t16) * 32 + q * 8];
#pragma unroll
        for (int ti = 0; ti < 2; ++ti)
            acc[ti] = mfma16(af[ti], bfr, acc[ti]);
    }

    // per-wave epilogue, no barriers
    const int lr = l >> 2, c4 = (l & 3) * 4;
#pragma unroll
    for (int ti = 0; ti < 2; ++ti) {
#pragma unroll
        for (int rg = 0; rg < 4; ++rg)
            epi[w][q * 4 + rg][t16] = acc[ti][rg];
        f4v v = *(const f4v*)&epi[w][lr][c4];
        int b = row0 + wr * 32 + ti * 16 + lr;
        size_t xi = ((size_t)b * L_SEQ + t) * D_DIM + col0 + wc * 16 + c4;
        s4v x = *(const s4v*)&XE[xi];
        s4v o;
#pragma unroll
        for (int u = 0; u < 4; ++u)
            o[u] = (short)f2bf(fast_tanh(bf2f((unsigned short)x[u]) + v[u]));
        *(s4v*)&XE[xi] = o;
    }
}

// ---------------------------------------------------------------------------
// k_mlp_mfma: h = tanh(concat(XE[i],XE[j]) @ W1 + b1) fused with rule-dot.
// 128x128 tile, K=2048, manual staging + prefetch, XCD swizzle (A-gather L2
// locality: each XCD owns 64 row-tiles, col-chunks dispatch-adjacent).
// ---------------------------------------------------------------------------
__global__ __launch_bounds__(256) void k_mlp_mfma(
    const int* __restrict__ i_idx, const int* __restrict__ j_idx,
    const bf16_t* __restrict__ XE, const bf16_t* __restrict__ W1T,
    const float* __restrict__ b1, const bf16_t* __restrict__ Wt2,
    const int* __restrict__ r_idx, float* __restrict__ partials)
{
    __shared__ bf16_t As[128 * 32];            // 8 KB
    __shared__ bf16_t Bs[128 * 32];            // 8 KB

    const int bi  = blockIdx.x;
    const int xcd = bi & 7, j = bi >> 3;
    const int rowTile = (xcd << 6) + (j >> 3);        // [0,512)
    const int colTile = j & 7;                        // [0,8)
    const int row0 = rowTile * 128, col0 = colTile * 128;

    const int tid = threadIdx.x;
    const int w = tid >> 6, l = tid & 63;
    const int q = l >> 4, t16 = l & 15;
    const int wm = (w >> 1) * 64, wn = (w & 1) * 64;

    const bf16_t* pi[2]; const bf16_t* pj[2];
#pragma unroll
    for (int r = 0; r < 2; ++r) {
        int m = row0 + (tid >> 2) + r * 64;
        pi[r] = XE + (size_t)i_idx[m] * D_DIM + ((tid & 3) << 3);
        pj[r] = XE + (size_t)j_idx[m] * D_DIM - D_DIM + ((tid & 3) << 3);  // k in [1024,2048)
    }
    const bf16_t* brow[2];
#pragma unroll
    for (int r = 0; r < 2; ++r)
        brow[r] = W1T + (size_t)(col0 + (tid >> 2) + r * 64) * (2 * D_DIM) + ((tid & 3) << 3);

    f4v acc[4][4];
#pragma unroll
    for (int i = 0; i < 4; ++i)
#pragma unroll
        for (int jj = 0; jj < 4; ++jj) acc[i][jj] = (f4v)0.f;

    // prefetch k=0
    s8v a0 = *(const s8v*)(pi[0]);
    s8v a1 = *(const s8v*)(pi[1]);
    s8v b0 = *(const s8v*)(brow[0]);
    s8v b1v = *(const s8v*)(brow[1]);

    const int rr = tid >> 2, cc = (tid & 3) << 3;
    for (int k0 = 0; k0 < 2 * D_DIM; k0 += 32) {
        __syncthreads();
        *(s8v*)&As[rr * 32 + cc]        = a0;
        *(s8v*)&As[(rr + 64) * 32 + cc] = a1;
        *(s8v*)&Bs[rr * 32 + cc]        = b0;
        *(s8v*)&Bs[(rr + 64) * 32 + cc] = b1v;
        int kn = k0 + 32;
        if (kn < 2 * D_DIM) {
            a0  = *(const s8v*)(((kn < D_DIM) ? pi[0] : pj[0]) + kn);
            a1  = *(const s8v*)(((kn < D_DIM) ? pi[1] : pj[1]) + kn);
            b0  = *(const s8v*)(brow[0] + kn);
            b1v = *(const s8v*)(brow[1] + kn);
        }
        __syncthreads();
        s8v af[4], bfr[4];
#pragma unroll
        for (int ti = 0; ti < 4; ++ti)
            af[ti] = *(const s8v*)&As[(wm + ti * 16 + t16) * 32 + q * 8];
#pragma unroll
        for (int tj = 0; tj < 4; ++tj)
            bfr[tj] = *(const s8v*)&Bs[(wn + tj * 16 + t16) * 32 + q * 8];
#pragma unroll
        for (int ti = 0; ti < 4; ++ti)
#pragma unroll
            for (int tj = 0; tj < 4; ++tj)
                acc[ti][tj] = mfma16(af[ti], bfr[tj], acc[ti][tj]);
    }

    // fused epilogue in C-layout: fast_tanh, dot with gathered rule row, 16-lane reduce
    const int cb = colTile * 2 + (w & 1);
#pragma unroll
    for (int ti = 0; ti < 4; ++ti) {
#pragma unroll
        for (int rg = 0; rg < 4; ++rg) {
            int m = row0 + wm + ti * 16 + q * 4 + rg;
            int r = r_idx[m];
            const bf16_t* wrow = Wt2 + (size_t)r * D_DIM + col0 + wn + t16;
            float pd = 0.f;
#pragma unroll
            for (int tj = 0; tj < 4; ++tj) {
                int col = col0 + wn + tj * 16 + t16;
                float h = fast_tanh(acc[ti][tj][rg] + b1[col]);
                pd += h * bf2f(wrow[tj * 16]);
            }
            pd += __shfl_xor(pd, 1);
            pd += __shfl_xor(pd, 2);
            pd += __shfl_xor(pd, 4);
            pd += __shfl_xor(pd, 8);
            if (t16 == 0)
                partials[(size_t)cb * M_NODES + m] = pd;
        }
    }
}

// ---------------------------------------------------------------------------
__global__ __launch_bounds__(256) void k_reduce(
    const float* __restrict__ partials, const int* __restrict__ r_idx,
    const float* __restrict__ b2, float* __restrict__ out)
{
    int m = blockIdx.x * 256 + threadIdx.x;
    float s = 0.f;
#pragma unroll
    for (int cb = 0; cb < 16; ++cb)
        s += partials[(size_t)cb * M_NODES + m];
    out[m] = s + b2[r_idx[m]];
}

// ---------------------------------------------------------------------------
extern "C" void kernel_launch(void* const* d_in, const int* in_sizes, int n_in,
                              void* d_out, int out_size, void* d_ws, size_t ws_size,
                              hipStream_t stream) {
    const int*   tokens = (const int*)  d_in[0];
    const int*   i_idx  = (const int*)  d_in[1];
    const int*   j_idx  = (const int*)  d_in[2];
    const int*   r_idx  = (const int*)  d_in[3];
    const float* emb    = (const float*)d_in[4];
    const float* Wxh    = (const float*)d_in[5];
    const float* Whh    = (const float*)d_in[6];
    const float* bh     = (const float*)d_in[7];
    const float* h0     = (const float*)d_in[8];
    const float* W1     = (const float*)d_in[9];
    const float* b1     = (const float*)d_in[10];
    const float* W2     = (const float*)d_in[11];
    const float* b2     = (const float*)d_in[12];
    float* out = (float*)d_out;

    // Workspace (~156 MiB). embB (20 MiB) aliases WhhT/W1T/Wt2 (22 MiB):
    // embB dead after k_xw_mfma; those conversions run after it.
    bf16_t* XE   = (bf16_t*)d_ws;                        // [B*L][D]  128 MiB
    bf16_t* WxhT = XE   + (size_t)M_NODES * D_DIM;       // [D][D]      2 MiB
    bf16_t* WhhT = WxhT + (size_t)D_DIM * D_DIM;         // [D][D]      2 MiB
    bf16_t* W1T  = WhhT + (size_t)D_DIM * D_DIM;         // [D][2D]     4 MiB
    bf16_t* Wt2  = W1T  + (size_t)2 * D_DIM * D_DIM;     // [R][D]     16 MiB
    bf16_t* embB = WhhT;                                 // [V][D]     20 MiB (alias)
    bf16_t* h0b  = Wt2  + (size_t)R_RULES * D_DIM;       // [D] (pad 2048)
    float*  par  = (float*)(h0b + 2048);                 // [16][M]     4 MiB

    // Phase 1: emb->bf16, Wxh, h0
    k_cvt_emb<<<V_VOCAB * D_DIM / 2048, 256, 0, stream>>>(emb, embB);
    k_transcvt<<<dim3(D_DIM / 32, D_DIM / 32), dim3(32, 8), 0, stream>>>(Wxh, WxhT, D_DIM, D_DIM);
    k_cvt_h0<<<1, 256, 0, stream>>>(h0, h0b);

    // Phase 2: XE = bf16(embB[tokens] @ Wxh + bh)   (last reader of embB)
    k_xw_mfma<<<4096, 256, 0, stream>>>(tokens, embB, WxhT, bh, XE);

    // Phase 3: remaining weight conversions (overwrite embB region)
    k_transcvt<<<dim3(D_DIM / 32, D_DIM / 32), dim3(32, 8), 0, stream>>>(Whh, WhhT, D_DIM, D_DIM);
    k_transcvt<<<dim3(D_DIM / 32, 2 * D_DIM / 32), dim3(32, 8), 0, stream>>>(W1, W1T, 2 * D_DIM, D_DIM);
    k_transcvt<<<dim3(R_RULES / 32, D_DIM / 32), dim3(32, 8), 0, stream>>>(W2, Wt2, D_DIM, R_RULES);

    // Phase 4: 64 sequential RNN steps (in-place on XE)
    for (int t = 0; t < L_SEQ; ++t) {
        const bf16_t* Abase = (t == 0) ? h0b : (XE + (size_t)(t - 1) * D_DIM);
        int strideRow       = (t == 0) ? 0   : L_SEQ * D_DIM;
        k_step_mfma<<<dim3(B_BATCH / 64, D_DIM / 64), 512, 0, stream>>>(
            Abase, strideRow, WhhT, XE, t);
    }

    // Phase 5: MLP + fused rule-dot partials
    k_mlp_mfma<<<4096, 256, 0, stream>>>(
        i_idx, j_idx, XE, W1T, b1, Wt2, r_idx, par);

    // Phase 6: deterministic reduce + b2
    k_reduce<<<M_NODES / 256, 256, 0, stream>>>(par, r_idx, b2, out);
}